// Round 9
// baseline (198.246 us; speedup 1.0000x reference)
//
#include <hip/hip_runtime.h>
#include <hip/hip_bf16.h>

// Problem constants: B=2, T=2048, D=1024, H=16, HD=64

typedef __attribute__((ext_vector_type(8))) short bf16x8;
typedef __attribute__((ext_vector_type(4))) float f32x4;
typedef __attribute__((ext_vector_type(16))) float f32x16;

#if __has_builtin(__builtin_amdgcn_exp2f)
#define EXP2(x) __builtin_amdgcn_exp2f(x)
#else
#define EXP2(x) exp2f(x)
#endif

__device__ __forceinline__ short f2b(float f) {
    __hip_bfloat16 h = __float2bfloat16(f);
    union { __hip_bfloat16 h; short s; } u; u.h = h;
    return u.s;
}

// v_permlane32_swap_b32 semantics (HW-validated by R5's passing PV path):
//   x' = {x.lo31, y.lo31}   (x'[i>=32] = y[i-32])
//   y' = {x.hi31, y.hi31}   (y'[i<32]  = x[i+32])
// MUST go through the builtin (or have compiler-visible instruction
// boundaries): gfx950 has a VALU-write -> permlane-read hazard that the
// compiler's hazard recognizer covers ONLY for instructions it can see.
// R6/R7 packed copies+swap into one asm blob -> stale reads -> absmax 1.6e4.
#if __has_builtin(__builtin_amdgcn_permlane32_swap)
#define HAS_PLSWAP 1
#else
#define HAS_PLSWAP 0
#endif

__device__ __forceinline__ void plswap(int& x, int& y) {
#if HAS_PLSWAP
    auto r = __builtin_amdgcn_permlane32_swap(x, y, false, false);
    x = (int)r[0]; y = (int)r[1];
#else
    asm("v_permlane32_swap_b32 %0, %1" : "+v"(x), "+v"(y));
#endif
}

__device__ __forceinline__ float xhalf_max(float x) {
    union { float f; int i; } u; u.f = x;
    int a = u.i, b = u.i;
#if HAS_PLSWAP
    auto r = __builtin_amdgcn_permlane32_swap(a, b, false, false);
    a = (int)r[0]; b = (int)r[1];
#else
    asm("v_mov_b32 %0, %2\n\t"
        "v_mov_b32 %1, %2\n\t"
        "s_nop 1\n\t"
        "v_permlane32_swap_b32 %0, %1"
        : "=&v"(a), "=&v"(b) : "v"(x));
#endif
    union { int i; float f; } fa, fb; fa.i = a; fb.i = b;
    return fmaxf(fa.f, fb.f);
}

__device__ __forceinline__ float xhalf_sum(float x) {
    union { float f; int i; } u; u.f = x;
    int a = u.i, b = u.i;
#if HAS_PLSWAP
    auto r = __builtin_amdgcn_permlane32_swap(a, b, false, false);
    a = (int)r[0]; b = (int)r[1];
#else
    asm("v_mov_b32 %0, %2\n\t"
        "v_mov_b32 %1, %2\n\t"
        "s_nop 1\n\t"
        "v_permlane32_swap_b32 %0, %1"
        : "=&v"(a), "=&v"(b) : "v"(x));
#endif
    union { int i; float f; } fa, fb; fa.i = a; fb.i = b;
    return fa.f + fb.f;
}

#define GLOAD_LDS16(gp, lp)                                                        \
    __builtin_amdgcn_global_load_lds(                                              \
        (const __attribute__((address_space(1))) unsigned int*)(gp),               \
        (__attribute__((address_space(3))) unsigned int*)(lp), 16, 0, 0)

// ---------------------------------------------------------------------------
// x fp32 -> bf16, 8 elements/thread
// ---------------------------------------------------------------------------
__global__ __launch_bounds__(256) void xcvt_kernel(
    const float* __restrict__ in, short* __restrict__ out) {
    const int i = (blockIdx.x * 256 + threadIdx.x) * 8;
    float4 v0 = *reinterpret_cast<const float4*>(in + i);
    float4 v1 = *reinterpret_cast<const float4*>(in + i + 4);
    union { short s[8]; uint4 q; } pk;
    pk.s[0] = f2b(v0.x); pk.s[1] = f2b(v0.y); pk.s[2] = f2b(v0.z); pk.s[3] = f2b(v0.w);
    pk.s[4] = f2b(v1.x); pk.s[5] = f2b(v1.y); pk.s[6] = f2b(v1.z); pk.s[7] = f2b(v1.w);
    *reinterpret_cast<uint4*>(out + i) = pk.q;
}

// ---------------------------------------------------------------------------
// Transpose + fp32->bf16 convert:  in[R][C] fp32  ->  out[C][R] bf16
// ---------------------------------------------------------------------------
__global__ __launch_bounds__(256) void transpose_w_kernel(
    const float* __restrict__ in, short* __restrict__ out, int R, int C) {
    __shared__ short lds[64][72];
    const int t = threadIdx.x;
    const int r0 = blockIdx.y * 64, c0 = blockIdx.x * 64;
    {
        const int ri = t >> 2, cb = (t & 3) * 16;
        const float* src = in + (size_t)(r0 + ri) * C + c0 + cb;
#pragma unroll
        for (int i = 0; i < 16; i += 4) {
            float4 v = *reinterpret_cast<const float4*>(src + i);
            lds[cb + i + 0][ri] = f2b(v.x);
            lds[cb + i + 1][ri] = f2b(v.y);
            lds[cb + i + 2][ri] = f2b(v.z);
            lds[cb + i + 3][ri] = f2b(v.w);
        }
    }
    __syncthreads();
    {
        const int co = t >> 2, rb = (t & 3) * 16;
        short* dst = out + (size_t)(c0 + co) * R + r0 + rb;
        *reinterpret_cast<uint4*>(dst)     = *reinterpret_cast<const uint4*>(&lds[co][rb]);
        *reinterpret_cast<uint4*>(dst + 8) = *reinterpret_cast<const uint4*>(&lds[co][rb + 8]);
    }
}

// ---------------------------------------------------------------------------
// GEMM1: qkv = xb @ WqkvT^T + bqkv   (bf16 in, fp32 acc)
// 128x128 tile, BK=32, 4 waves, 2-phase dbuf global_load_lds, XCD swizzle.
// Q pre-scaled by 0.125*log2(e). Epilogue: q,k -> [bh][t][64]; v -> [bh][64][t].
// ---------------------------------------------------------------------------
__global__ __launch_bounds__(256) void gemm1_kernel(
    const short* __restrict__ XB, const short* __restrict__ WT,
    const float* __restrict__ bqkv,
    short* __restrict__ qb, short* __restrict__ kb, short* __restrict__ vtb) {
    __shared__ short a_lds[2][128 * 32];
    __shared__ short b_lds[2][128 * 32];
    const int tid = threadIdx.x;
    const int lane = tid & 63, w = tid >> 6;
    const int wr = w >> 1, wc = w & 1;
    const int lin = blockIdx.x + 24 * blockIdx.y;     // nwg=768, 768%8==0
    const int swz = (lin & 7) * 96 + (lin >> 3);
    const int m0 = (swz / 24) * 128, n0 = (swz % 24) * 128;
    f32x4 acc[4][4] = {};

    const int srow0 = tid >> 2, ssl = tid & 3;
    const int slc0 = (ssl ^ ((srow0 >> 1) & 3)) * 8;
    const int srow1 = srow0 + 64;
    const int slc1 = (ssl ^ ((srow1 >> 1) & 3)) * 8;

#define G1_STAGE(bufi, kk)                                                          \
    do {                                                                            \
        GLOAD_LDS16(XB + (size_t)(m0 + srow0) * 1024 + (kk) + slc0,                 \
                    &a_lds[bufi][(w * 64) * 8]);                                    \
        GLOAD_LDS16(WT + (size_t)(n0 + srow0) * 1024 + (kk) + slc0,                 \
                    &b_lds[bufi][(w * 64) * 8]);                                    \
        GLOAD_LDS16(XB + (size_t)(m0 + srow1) * 1024 + (kk) + slc1,                 \
                    &a_lds[bufi][(256 + w * 64) * 8]);                              \
        GLOAD_LDS16(WT + (size_t)(n0 + srow1) * 1024 + (kk) + slc1,                 \
                    &b_lds[bufi][(256 + w * 64) * 8]);                              \
    } while (0)

    G1_STAGE(0, 0);
    __syncthreads();
    int cur = 0;
    for (int k0 = 0; k0 < 1024; k0 += 32) {
        if (k0 + 32 < 1024) G1_STAGE(cur ^ 1, k0 + 32);
        bf16x8 af[4], bfv[4];
#pragma unroll
        for (int mi = 0; mi < 4; ++mi) {
            const int rA = wr * 64 + mi * 16 + (lane & 15);
            const int sl = (lane >> 4) ^ ((rA >> 1) & 3);
            af[mi] = *reinterpret_cast<const bf16x8*>(&a_lds[cur][rA * 32 + sl * 8]);
        }
#pragma unroll
        for (int nj = 0; nj < 4; ++nj) {
            const int rB = wc * 64 + nj * 16 + (lane & 15);
            const int sl = (lane >> 4) ^ ((rB >> 1) & 3);
            bfv[nj] = *reinterpret_cast<const bf16x8*>(&b_lds[cur][rB * 32 + sl * 8]);
        }
#pragma unroll
        for (int mi = 0; mi < 4; ++mi)
#pragma unroll
            for (int nj = 0; nj < 4; ++nj)
                acc[mi][nj] = __builtin_amdgcn_mfma_f32_16x16x32_bf16(af[mi], bfv[nj], acc[mi][nj], 0, 0, 0);
        __syncthreads();
        cur ^= 1;
    }

    const float QSCL = 0.125f * 1.44269504088896340736f;   // 1/sqrt(64)*log2(e)
#pragma unroll
    for (int mi = 0; mi < 4; ++mi) {
#pragma unroll
        for (int nj = 0; nj < 4; ++nj) {
            const int row0 = m0 + wr * 64 + mi * 16 + ((lane >> 4) << 2);
            const int col  = n0 + wc * 64 + nj * 16 + (lane & 15);
            const float bias = bqkv[col];
            const int sec = col >> 10;
            const int h = (col & 1023) >> 6, d = col & 63;
            const int b = row0 >> 11;
            const int bh = b * 16 + h;
            if (sec == 2) {
                const int t0 = row0 & 2047;
                union { short s[4]; uint2 u; } pk;
#pragma unroll
                for (int r = 0; r < 4; ++r) pk.s[r] = f2b(acc[mi][nj][r] + bias);
                *reinterpret_cast<uint2*>(vtb + (size_t)(bh * 64 + d) * 2048 + t0) = pk.u;
            } else if (sec == 0) {
#pragma unroll
                for (int r = 0; r < 4; ++r) {
                    const int t = (row0 & 2047) + r;
                    qb[(size_t)(bh * 2048 + t) * 64 + d] = f2b((acc[mi][nj][r] + bias) * QSCL);
                }
            } else {
#pragma unroll
                for (int r = 0; r < 4; ++r) {
                    const int t = (row0 & 2047) + r;
                    kb[(size_t)(bh * 2048 + t) * 64 + d] = f2b(acc[mi][nj][r] + bias);
                }
            }
        }
    }
}

// ---------------------------------------------------------------------------
// Flash attention, 32x32x16 swapped structure, in-register P (T12).
// WG = 256 thr (4 waves x 32 q-rows), QBLK=128, KVBLK=64, K/V 2-phase dbuf.
// Cross-half (^32) row-max via permlane32_swap BUILTIN (hazard-safe).
// l is kept as per-half partial sum; single cross-half combine in epilogue.
// ---------------------------------------------------------------------------
__global__ __launch_bounds__(256) void attn_kernel(
    const short* __restrict__ qb, const short* __restrict__ kb,
    const short* __restrict__ vtb, short* __restrict__ ctx) {
    __shared__ short k_lds[2][64 * 64];
    __shared__ short v_lds[2][64 * 64];
    const int tid = threadIdx.x, lane = tid & 63, w = tid >> 6;
    const int q31 = lane & 31, hi = lane >> 5;

    // bh-grouped swizzle: dispatch d -> XCD d&7 owns bh in [4*(d&7), 4*(d&7)+4)
    const int dlin = blockIdx.x + 16 * (blockIdx.y + 16 * blockIdx.z);
    const int xcd = dlin & 7, ii = dlin >> 3;
    const int bh = xcd * 4 + (ii >> 4);
    const int qblk = ii & 15;
    const int b = bh >> 4, h = bh & 15;
    const int tq = qblk * 128 + w * 32 + q31;

    // Q B-frags (B-layout: col=lane&31, k=(lane>>5)*8+j): qf[s] = Q[tq][16s+8hi..]
    bf16x8 qf[4];
#pragma unroll
    for (int s = 0; s < 4; ++s)
        qf[s] = *reinterpret_cast<const bf16x8*>(
            qb + (size_t)(bh * 2048 + tq) * 64 + s * 16 + hi * 8);

    const int srow_l = lane >> 3, ssl = lane & 7;
    const int row_a = w * 8 + srow_l;          // rep 0 row
    const int row_b = 32 + w * 8 + srow_l;     // rep 1 row
    const int lc_a = (ssl ^ (row_a & 7)) * 8;
    const int lc_b = (ssl ^ (row_b & 7)) * 8;

#define ATT_STAGE(bufi, kv)                                                         \
    do {                                                                            \
        GLOAD_LDS16(kb + (size_t)(bh * 2048 + (kv) + row_a) * 64 + lc_a,            \
                    &k_lds[bufi][(w * 8) * 64]);                                    \
        GLOAD_LDS16(vtb + (size_t)(bh * 64 + row_a) * 2048 + (kv) + lc_a,           \
                    &v_lds[bufi][(w * 8) * 64]);                                    \
        GLOAD_LDS16(kb + (size_t)(bh * 2048 + (kv) + row_b) * 64 + lc_b,            \
                    &k_lds[bufi][(32 * 64) + (w * 8) * 64]);                        \
        GLOAD_LDS16(vtb + (size_t)(bh * 64 + row_b) * 2048 + (kv) + lc_b,           \
                    &v_lds[bufi][(32 * 64) + (w * 8) * 64]);                        \
    } while (0)

    f32x16 o0 = {}, o1 = {};
    float m_s = -1e30f, l_s = 0.f;   // l_s = OWN-half partial sum

    ATT_STAGE(0, 0);
    __syncthreads();
    int cur = 0;
    for (int kv0 = 0; kv0 < 2048; kv0 += 64) {
        if (kv0 + 64 < 2048) ATT_STAGE(cur ^ 1, kv0 + 64);

        // S^T: sA0 = kv rows 0..31, sA1 = 32..63 (col = q31)
        f32x16 sA0 = {}, sA1 = {};
#pragma unroll
        for (int s = 0; s < 4; ++s) {
            {
                const int row = q31;
                const int sl = (2 * s + hi) ^ (row & 7);
                bf16x8 kf = *reinterpret_cast<const bf16x8*>(&k_lds[cur][row * 64 + sl * 8]);
                sA0 = __builtin_amdgcn_mfma_f32_32x32x16_bf16(kf, qf[s], sA0, 0, 0, 0);
            }
            {
                const int row = 32 + q31;
                const int sl = (2 * s + hi) ^ (row & 7);
                bf16x8 kf = *reinterpret_cast<const bf16x8*>(&k_lds[cur][row * 64 + sl * 8]);
                sA1 = __builtin_amdgcn_mfma_f32_32x32x16_bf16(kf, qf[s], sA1, 0, 0, 0);
            }
        }

        // row max: in-lane tree + hazard-safe cross-half combine
        float mA[8];
#pragma unroll
        for (int e = 0; e < 8; ++e)
            mA[e] = fmaxf(fmaxf(sA0[e], sA0[e + 8]), fmaxf(sA1[e], sA1[e + 8]));
        float mx = fmaxf(fmaxf(fmaxf(mA[0], mA[1]), fmaxf(mA[2], mA[3])),
                         fmaxf(fmaxf(mA[4], mA[5]), fmaxf(mA[6], mA[7])));
        mx = xhalf_max(mx);

        const float mn = fmaxf(m_s, mx);
        if (__any(mn - m_s > 8.f)) {                      // defer-max (T13)
            const float alpha = EXP2(m_s - mn);
            m_s = mn;
            l_s *= alpha;                                 // per-half partial, shared m
#pragma unroll
            for (int e = 0; e < 16; ++e) { o0[e] *= alpha; o1[e] *= alpha; }
        }

        // exp + pack to bf16 pairs: W[m] = cvt_pk(p[2m], p[2m+1])
        float rs0 = 0.f, rs1 = 0.f, rs2 = 0.f, rs3 = 0.f;
        int W0[8], W1[8];
#pragma unroll
        for (int m2 = 0; m2 < 8; ++m2) {
            float p0 = EXP2(sA0[2 * m2] - m_s);
            float p1 = EXP2(sA0[2 * m2 + 1] - m_s);
            rs0 += p0; rs1 += p1;
            asm("v_cvt_pk_bf16_f32 %0, %1, %2" : "=v"(W0[m2]) : "v"(p0), "v"(p1));
            float p2 = EXP2(sA1[2 * m2] - m_s);
            float p3 = EXP2(sA1[2 * m2 + 1] - m_s);
            rs2 += p2; rs3 += p3;
            asm("v_cvt_pk_bf16_f32 %0, %1, %2" : "=v"(W1[m2]) : "v"(p2), "v"(p3));
        }
        l_s += (rs0 + rs1) + (rs2 + rs3);                 // own half only

        // PV: B-frag via permlane32_swap (builtin; lane gets partner's words)
#pragma unroll
        for (int s = 0; s < 4; ++s) {
            const int base = (s & 1) * 4;
            int x0, x1, y0, y1;
            if (s < 2) { x0 = W0[base]; x1 = W0[base + 1]; y0 = W0[base + 2]; y1 = W0[base + 3]; }
            else       { x0 = W1[base]; x1 = W1[base + 1]; y0 = W1[base + 2]; y1 = W1[base + 3]; }
            plswap(x0, y0);
            plswap(x1, y1);
            union { int w[4]; bf16x8 v; } pf;
            pf.w[0] = x0; pf.w[1] = x1; pf.w[2] = y0; pf.w[3] = y1;
            {
                const int row = q31;
                const int sl = (2 * s + hi) ^ (row & 7);
                bf16x8 vf = *reinterpret_cast<const bf16x8*>(&v_lds[cur][row * 64 + sl * 8]);
                o0 = __builtin_amdgcn_mfma_f32_32x32x16_bf16(vf, pf.v, o0, 0, 0, 0);
            }
            {
                const int row = 32 + q31;
                const int sl = (2 * s + hi) ^ (row & 7);
                bf16x8 vf = *reinterpret_cast<const bf16x8*>(&v_lds[cur][row * 64 + sl * 8]);
                o1 = __builtin_amdgcn_mfma_f32_32x32x16_bf16(vf, pf.v, o1, 0, 0, 0);
            }
        }
        __syncthreads();
        cur ^= 1;
    }

    // epilogue: single cross-half l combine, normalize, store
    const float linv = 1.0f / xhalf_sum(l_s);
#pragma unroll
    for (int e = 0; e < 16; ++e) { o0[e] *= linv; o1[e] *= linv; }
    short* cbase = ctx + (size_t)(b * 2048 + tq) * 1024 + h * 64 + 4 * hi;
#pragma unroll
    for (int blk = 0; blk < 4; ++blk) {
        union { short s4[4]; uint2 u; } pk0, pk1;
#pragma unroll
        for (int r = 0; r < 4; ++r) {
            pk0.s4[r] = f2b(o0[4 * blk + r]);
            pk1.s4[r] = f2b(o1[4 * blk + r]);
        }
        *reinterpret_cast<uint2*>(cbase + 8 * blk)      = pk0.u;
        *reinterpret_cast<uint2*>(cbase + 32 + 8 * blk) = pk1.u;
    }
}

// ---------------------------------------------------------------------------
// GEMM2: out = ctx @ WoutT^T + bout   (bf16 in, fp32 out). 2-phase dbuf.
// ---------------------------------------------------------------------------
__global__ __launch_bounds__(256) void gemm2_kernel(
    const short* __restrict__ CTX, const short* __restrict__ WT,
    const float* __restrict__ bout, float* __restrict__ out) {
    __shared__ short a_lds[2][128 * 32];
    __shared__ short b_lds[2][128 * 32];
    const int tid = threadIdx.x;
    const int lane = tid & 63, w = tid >> 6;
    const int wr = w >> 1, wc = w & 1;
    const int lin = blockIdx.x + 8 * blockIdx.y;      // nwg=256
    const int swz = (lin & 7) * 32 + (lin >> 3);
    const int m0 = (swz >> 3) * 128, n0 = (swz & 7) * 128;
    f32x4 acc[4][4] = {};

    const int srow0 = tid >> 2, ssl = tid & 3;
    const int slc0 = (ssl ^ ((srow0 >> 1) & 3)) * 8;
    const int srow1 = srow0 + 64;
    const int slc1 = (ssl ^ ((srow1 >> 1) & 3)) * 8;

#define G2_STAGE(bufi, kk)                                                          \
    do {                                                                            \
        GLOAD_LDS16(CTX + (size_t)(m0 + srow0) * 1024 + (kk) + slc0,                \
                    &a_lds[bufi][(w * 64) * 8]);                                    \
        GLOAD_LDS16(WT + (size_t)(n0 + srow0) * 1024 + (kk) + slc0,                 \
                    &b_lds[bufi][(w * 64) * 8]);                                    \
        GLOAD_LDS16(CTX + (size_t)(m0 + srow1) * 1024 + (kk) + slc1,                \
                    &a_lds[bufi][(256 + w * 64) * 8]);                              \
        GLOAD_LDS16(WT + (size_t)(n0 + srow1) * 1024 + (kk) + slc1,                 \
                    &b_lds[bufi][(256 + w * 64) * 8]);                              \
    } while (0)

    G2_STAGE(0, 0);
    __syncthreads();
    int cur = 0;
    for (int k0 = 0; k0 < 1024; k0 += 32) {
        if (k0 + 32 < 1024) G2_STAGE(cur ^ 1, k0 + 32);
        bf16x8 af[4], bfv[4];
#pragma unroll
        for (int mi = 0; mi < 4; ++mi) {
            const int rA = wr * 64 + mi * 16 + (lane & 15);
            const int sl = (lane >> 4) ^ ((rA >> 1) & 3);
            af[mi] = *reinterpret_cast<const bf16x8*>(&a_lds[cur][rA * 32 + sl * 8]);
        }
#pragma unroll
        for (int nj = 0; nj < 4; ++nj) {
            const int rB = wc * 64 + nj * 16 + (lane & 15);
            const int sl = (lane >> 4) ^ ((rB >> 1) & 3);
            bfv[nj] = *reinterpret_cast<const bf16x8*>(&b_lds[cur][rB * 32 + sl * 8]);
        }
#pragma unroll
        for (int mi = 0; mi < 4; ++mi)
#pragma unroll
            for (int nj = 0; nj < 4; ++nj)
                acc[mi][nj] = __builtin_amdgcn_mfma_f32_16x16x32_bf16(af[mi], bfv[nj], acc[mi][nj], 0, 0, 0);
        __syncthreads();
        cur ^= 1;
    }

#pragma unroll
    for (int mi = 0; mi < 4; ++mi) {
#pragma unroll
        for (int nj = 0; nj < 4; ++nj) {
            const int row0 = m0 + wr * 64 + mi * 16 + ((lane >> 4) << 2);
            const int col  = n0 + wc * 64 + nj * 16 + (lane & 15);
            const float bias = bout[col];
#pragma unroll
            for (int r = 0; r < 4; ++r)
                out[(size_t)(row0 + r) * 1024 + col] = acc[mi][nj][r] + bias;
        }
    }
}

// ---------------------------------------------------------------------------
extern "C" void kernel_launch(void* const* d_in, const int* in_sizes, int n_in,
                              void* d_out, int out_size, void* d_ws, size_t ws_size,
                              hipStream_t stream) {
    const float* x    = (const float*)d_in[0];
    const float* Wqkv = (const float*)d_in[1];
    const float* bqkv = (const float*)d_in[2];
    const float* Wout = (const float*)d_in[3];
    const float* bout = (const float*)d_in[4];
    float* out = (float*)d_out;

    const size_t MB = 1u << 20;
    if (ws_size < 40 * MB) return;

    char* ws = (char*)d_ws;
    short* qb    = (short*)(ws + 0 * MB);    // [2][16][2048][64] bf16  (8 MB)
    short* kb    = (short*)(ws + 8 * MB);    // [2][16][2048][64] bf16  (8 MB)
    short* vtb   = (short*)(ws + 16 * MB);   // [2][16][64][2048] bf16  (8 MB)
    short* xbctx = (short*)(ws + 24 * MB);   // xb for gemm1, then ctx  (8 MB)
    short* wqkvT = (short*)(ws + 32 * MB);   // [3072][1024] bf16       (6 MB)
    short* woutT = (short*)(ws + 38 * MB);   // [1024][1024] bf16       (2 MB)

    xcvt_kernel<<<2048, 256, 0, stream>>>(x, xbctx);
    transpose_w_kernel<<<dim3(48, 16), 256, 0, stream>>>(Wqkv, wqkvT, 1024, 3072);
    transpose_w_kernel<<<dim3(16, 16), 256, 0, stream>>>(Wout, woutT, 1024, 1024);
    gemm1_kernel<<<dim3(24, 32), 256, 0, stream>>>(xbctx, wqkvT, bqkv, qb, kb, vtb);
    attn_kernel<<<dim3(16, 16, 2), 256, 0, stream>>>(qb, kb, vtb, xbctx);
    gemm2_kernel<<<dim3(8, 32), 256, 0, stream>>>(xbctx, woutT, bout, out);
}